// Round 1
// baseline (224.876 us; speedup 1.0000x reference)
//
#include <hip/hip_runtime.h>
#include <math.h>

#define NB 8      // NUM_BATCHES
#define C  256    // channels
#define CR 64     // C / r

// ---------------------------------------------------------------------------
// Kernel 1: per-batch sums + counts.
// One wave (64 lanes) processes one row per iteration: lane l loads float4
// covering channels 4l..4l+3 (1 KB contiguous = perfectly coalesced).
// Each wave accumulates into its OWN LDS copy [8][256] -> no atomics, no
// cross-wave races. Block reduces 4 wave copies, then global atomicAdd.
// ---------------------------------------------------------------------------
__global__ __launch_bounds__(256) void pool_kernel(
    const float* __restrict__ x,      // [N, 256]
    const int*   __restrict__ bids,   // [N]
    float*       __restrict__ gsums,  // [8][256] (pre-zeroed)
    float*       __restrict__ gcnts,  // [8]      (pre-zeroed)
    int N)
{
    __shared__ float lsum[4][NB][C];   // 32 KB
    __shared__ float lcnt[4][NB];

    const int tid  = threadIdx.x;
    const int wid  = tid >> 6;
    const int lane = tid & 63;

    float* lsum_flat = &lsum[0][0][0];
    for (int i = tid; i < 4 * NB * C; i += 256) lsum_flat[i] = 0.f;
    if (tid < 4 * NB) (&lcnt[0][0])[tid] = 0.f;
    __syncthreads();

    const int waves_total = gridDim.x * 4;
    int gwave = blockIdx.x * 4 + wid;

    for (int row = gwave; row < N; row += waves_total) {
        const int bid = bids[row];
        const float4 v = ((const float4*)(x + (size_t)row * C))[lane];
        float* dst = &lsum[wid][bid][lane * 4];
        dst[0] += v.x; dst[1] += v.y; dst[2] += v.z; dst[3] += v.w;
        if (lane == 0) lcnt[wid][bid] += 1.f;
    }
    __syncthreads();

    // reduce the 4 per-wave copies, one global atomicAdd per element
    for (int i = tid; i < NB * C; i += 256) {
        float s = lsum[0][0][i] + lsum[1][0][i] + lsum[2][0][i] + lsum[3][0][i];
        atomicAdd(&gsums[i], s);
    }
    if (tid < NB) {
        float s = lcnt[0][tid] + lcnt[1][tid] + lcnt[2][tid] + lcnt[3][tid];
        atomicAdd(&gcnts[tid], s);
    }
}

// ---------------------------------------------------------------------------
// Kernel 2: tiny MLP. pooled = sums/max(cnt,1); h = relu(pooled@W1+b1);
// y = sigmoid(h@W2+b2). One block, 256 threads. ~0.5 MFLOP total.
// ---------------------------------------------------------------------------
__global__ __launch_bounds__(256) void mlp_kernel(
    const float* __restrict__ gsums,  // [8][256]
    const float* __restrict__ gcnts,  // [8]
    const float* __restrict__ W1,     // [256][64]
    const float* __restrict__ b1,     // [64]
    const float* __restrict__ W2,     // [64][256]
    const float* __restrict__ b2,     // [256]
    float*       __restrict__ y)      // [8][256] out
{
    __shared__ float pooled[NB][C];
    __shared__ float h[NB][CR];
    const int tid = threadIdx.x;

    for (int i = tid; i < NB * C; i += 256) {
        const float cnt = gcnts[i >> 8];                  // i / 256 = batch
        (&pooled[0][0])[i] = gsums[i] / fmaxf(cnt, 1.f);
    }
    __syncthreads();

    // h: 8*64 = 512 outputs, 2 per thread
    for (int o = tid; o < NB * CR; o += 256) {
        const int b = o >> 6, j = o & 63;
        float acc = b1[j];
        #pragma unroll 4
        for (int k = 0; k < C; ++k) acc = fmaf(pooled[b][k], W1[k * CR + j], acc);
        (&h[0][0])[o] = fmaxf(acc, 0.f);
    }
    __syncthreads();

    // y: 8*256 = 2048 outputs, 8 per thread
    for (int o = tid; o < NB * C; o += 256) {
        const int b = o >> 8, j = o & 255;
        float acc = b2[j];
        #pragma unroll
        for (int k = 0; k < CR; ++k) acc = fmaf(h[b][k], W2[k * C + j], acc);
        y[o] = 1.f / (1.f + __expf(-acc));
    }
}

// ---------------------------------------------------------------------------
// Kernel 3: out[row, :] = y[bids[row], :] * x[row, :].
// One wave per row, float4 per lane; y (8 KB) cached in LDS.
// ---------------------------------------------------------------------------
__global__ __launch_bounds__(256) void scale_kernel(
    const float* __restrict__ x,     // [N, 256]
    const int*   __restrict__ bids,  // [N]
    const float* __restrict__ y,     // [8][256]
    float*       __restrict__ out,   // [N, 256]
    int N)
{
    __shared__ float ly[NB][C];      // 8 KB
    const int tid = threadIdx.x;
    for (int i = tid; i < NB * C; i += 256) (&ly[0][0])[i] = y[i];
    __syncthreads();

    const int wid  = tid >> 6;
    const int lane = tid & 63;
    const int waves_total = gridDim.x * 4;
    int gwave = blockIdx.x * 4 + wid;

    for (int row = gwave; row < N; row += waves_total) {
        const int bid = bids[row];
        float4 v = ((const float4*)(x + (size_t)row * C))[lane];
        const float4 g = ((const float4*)&ly[bid][0])[lane];
        v.x *= g.x; v.y *= g.y; v.z *= g.z; v.w *= g.w;
        ((float4*)(out + (size_t)row * C))[lane] = v;
    }
}

extern "C" void kernel_launch(void* const* d_in, const int* in_sizes, int n_in,
                              void* d_out, int out_size, void* d_ws, size_t ws_size,
                              hipStream_t stream)
{
    const float* x    = (const float*)d_in[0];
    const int*   bids = (const int*)  d_in[1];
    const float* W1   = (const float*)d_in[2];
    const float* b1   = (const float*)d_in[3];
    const float* W2   = (const float*)d_in[4];
    const float* b2   = (const float*)d_in[5];
    float* out = (float*)d_out;

    const int N = in_sizes[1];           // 262144

    // workspace layout (floats): sums[2048] | cnts[8] | pad[8] | y[2048]
    float* gsums = (float*)d_ws;
    float* gcnts = gsums + NB * C;
    float* gy    = gcnts + 16;           // 16-float aligned

    // zero the accumulators (sums + counts) every call — ws is NOT re-poisoned
    hipMemsetAsync(d_ws, 0, (NB * C + NB) * sizeof(float), stream);

    pool_kernel<<<1024, 256, 0, stream>>>(x, bids, gsums, gcnts, N);
    mlp_kernel<<<1, 256, 0, stream>>>(gsums, gcnts, W1, b1, W2, b2, gy);
    scale_kernel<<<2048, 256, 0, stream>>>(x, bids, gy, out, N);
}